// Round 12
// baseline (109.934 us; speedup 1.0000x reference)
//
#include <hip/hip_runtime.h>

// Requires ws_size >= 48 MiB.
typedef short bf16x8 __attribute__((ext_vector_type(8)));
typedef float f32x4 __attribute__((ext_vector_type(4)));
typedef float f32x16 __attribute__((ext_vector_type(16)));
typedef unsigned short ushort8 __attribute__((ext_vector_type(8)));
typedef unsigned short ushort4v __attribute__((ext_vector_type(4)));
typedef unsigned int uint4v __attribute__((ext_vector_type(4)));
typedef unsigned short u16;

__device__ inline u16 f2bf(float f) {
  unsigned int u = __float_as_uint(f);
  u += 0x7fffu + ((u >> 16) & 1u);
  return (u16)(u >> 16);
}

__device__ inline unsigned cvt_pk_bf16(float lo, float hi2) {
  unsigned r;
  asm("v_cvt_pk_bf16_f32 %0, %1, %2" : "=v"(r) : "v"(lo), "v"(hi2));
  return r;
}

// NOTE: only safe with two DISTINCT live inputs (R5 bug: a==b coalesces).
__device__ inline void perm32swap(unsigned& a, unsigned& b) {
  asm("v_permlane32_swap_b32 %0, %1" : "+v"(a), "+v"(b));
}

__device__ inline void gload_lds16(const u16* g, u16* l) {
  __builtin_amdgcn_global_load_lds(
      (const __attribute__((address_space(1))) unsigned int*)g,
      (__attribute__((address_space(3))) unsigned int*)l, 16, 0, 0);
}

// Counted vmcnt wait + scheduling fence (rule #18).
#define WAITVM(NSTR)                          \
  do {                                        \
    asm volatile("s_waitcnt vmcnt(" NSTR ")"); \
    __builtin_amdgcn_sched_barrier(0);        \
  } while (0)

// ---------------- elementwise f32 -> bf16 ----------------
__global__ __launch_bounds__(256) void cvt_bf16(const float* __restrict__ in,
                                                u16* __restrict__ out, int n) {
  int i = (blockIdx.x * 256 + threadIdx.x) * 8;
  if (i >= n) return;
  float4 a = *(const float4*)(in + i);
  float4 b = *(const float4*)(in + i + 4);
  ushort8 o;
  o[0] = f2bf(a.x); o[1] = f2bf(a.y); o[2] = f2bf(a.z); o[3] = f2bf(a.w);
  o[4] = f2bf(b.x); o[5] = f2bf(b.y); o[6] = f2bf(b.z); o[7] = f2bf(b.w);
  *(ushort8*)(out + i) = o;
}

// ---------------- W[K][N] f32 -> Wt[N][K] bf16 ----------------
__global__ __launch_bounds__(256) void trans_w(const float* __restrict__ W,
                                               u16* __restrict__ Wt, int K, int N) {
  const int k0 = blockIdx.x * 64, n0 = blockIdx.y * 64;
  const int tx = threadIdx.x & 63, ty = threadIdx.x >> 6;
  __shared__ float t[64][65];
#pragma unroll
  for (int i = 0; i < 16; ++i) {
    int r = i * 4 + ty;
    t[r][tx] = W[(size_t)(k0 + r) * N + n0 + tx];
  }
  __syncthreads();
#pragma unroll
  for (int i = 0; i < 16; ++i) {
    int r = i * 4 + ty;
    Wt[(size_t)(n0 + r) * K + k0 + tx] = f2bf(t[tx][r]);
  }
}

// ---------------- GEMM: C[M][N] = A[M][K] * Bt[N][K]^T ----------------
// 2-phase pipelined; swizzled LDS; MODE 0: fragment-packed Q/K/V epilogue
// (Q scaled by 0.125*log2e so attention can use exp2 directly),
// MODE 1: bias + f32 out.
template <int MODE>
__global__ __launch_bounds__(256) void gemm_bt(
    const u16* __restrict__ A, const u16* __restrict__ Bt, int M, int N, int K,
    const float* __restrict__ bias, float* __restrict__ outF,
    u16* __restrict__ Qb, u16* __restrict__ Kb, u16* __restrict__ Vb) {
  const int bm = blockIdx.x * 128;
  const int bn = blockIdx.y * 128;
  const int tid = threadIdx.x;
  const int wid = tid >> 6;
  const int lr = tid & 15;
  const int lg = (tid >> 4) & 3;
  const int wr = wid >> 1, wc = wid & 1;

  __shared__ u16 smem[32768];
  u16* Ab0 = smem;
  u16* Ab1 = smem + 8192;
  u16* Bb0 = smem + 16384;
  u16* Bb1 = smem + 24576;

  f32x4 acc[4][4] = {};

  const int rowi = tid >> 3;
  const int sslot = ((tid & 7) ^ (rowi & 7)) * 8;
  const u16* Ag = A + (size_t)bm * K;
  const u16* Bg = Bt + (size_t)bn * K;
  const int nkt = K >> 6;

  auto stage = [&](u16* Ad, u16* Bd, int kt) {
    const int kof = kt << 6;
#pragma unroll
    for (int i = 0; i < 4; ++i) {
      const int row = i * 32 + rowi;
      gload_lds16(Ag + (size_t)row * K + kof + sslot, Ad + (i * 32 + wid * 8) * 64);
      gload_lds16(Bg + (size_t)row * K + kof + sslot, Bd + (i * 32 + wid * 8) * 64);
    }
  };

  stage(Ab0, Bb0, 0);
  __syncthreads();

  for (int kt = 0; kt < nkt; ++kt) {
    const int p = kt & 1;
    const char* Ard = (const char*)(p ? Ab1 : Ab0);
    const char* Brd = (const char*)(p ? Bb1 : Bb0);
    bf16x8 af[4], bfr[4];
#pragma unroll
    for (int t = 0; t < 4; ++t) {
      const int ra = wr * 64 + t * 16 + lr;
      const int rb = wc * 64 + t * 16 + lr;
      af[t] = *(const bf16x8*)(Ard + ra * 128 + ((lg * 16) ^ ((ra & 7) << 4)));
      bfr[t] = *(const bf16x8*)(Brd + rb * 128 + ((lg * 16) ^ ((rb & 7) << 4)));
    }
    if (kt + 1 < nkt) stage(p ? Ab0 : Ab1, p ? Bb0 : Bb1, kt + 1);
    __builtin_amdgcn_s_setprio(1);
#pragma unroll
    for (int mt = 0; mt < 4; ++mt)
#pragma unroll
      for (int nt = 0; nt < 4; ++nt)
        acc[mt][nt] = __builtin_amdgcn_mfma_f32_16x16x32_bf16(
            af[mt], bfr[nt], acc[mt][nt], 0, 0, 0);
    __builtin_amdgcn_s_setprio(0);
#pragma unroll
    for (int t = 0; t < 4; ++t) {
      const int ra = wr * 64 + t * 16 + lr;
      const int rb = wc * 64 + t * 16 + lr;
      af[t] = *(const bf16x8*)(Ard + ra * 128 + ((64 + lg * 16) ^ ((ra & 7) << 4)));
      bfr[t] = *(const bf16x8*)(Brd + rb * 128 + ((64 + lg * 16) ^ ((rb & 7) << 4)));
    }
    __builtin_amdgcn_s_setprio(1);
#pragma unroll
    for (int mt = 0; mt < 4; ++mt)
#pragma unroll
      for (int nt = 0; nt < 4; ++nt)
        acc[mt][nt] = __builtin_amdgcn_mfma_f32_16x16x32_bf16(
            af[mt], bfr[nt], acc[mt][nt], 0, 0, 0);
    __builtin_amdgcn_s_setprio(0);
    __syncthreads();
  }

  if (MODE == 1) {
#pragma unroll
    for (int mt = 0; mt < 4; ++mt) {
      const int row0 = bm + wr * 64 + mt * 16 + lg * 4;
#pragma unroll
      for (int nt = 0; nt < 4; ++nt) {
        const int col = bn + wc * 64 + nt * 16 + lr;
        const float bv = bias[col];
#pragma unroll
        for (int r = 0; r < 4; ++r)
          outF[(size_t)(row0 + r) * N + col] = acc[mt][nt][r] + bv;
      }
    }
    return;
  }

  u16* T = smem;
  const int which = bn >> 10;

  if (which == 2) {
#pragma unroll
    for (int nt = 0; nt < 4; ++nt) {
      const int cl = wc * 64 + nt * 16 + lr;
      const float bv = bias[bn + cl];
#pragma unroll
      for (int mt = 0; mt < 4; ++mt) {
        const int rlb = wr * 128 + mt * 32 + lg * 8;
        ushort4v pk;
#pragma unroll
        for (int r = 0; r < 4; ++r) pk[r] = f2bf(acc[mt][nt][r] + bv);
        *(ushort4v*)((char*)T + cl * 256 + (rlb ^ ((cl & 7) << 4))) = pk;
      }
    }
  } else {
    // Q gets 0.125 (1/sqrt(64)) * log2(e) so flash can use exp2 directly.
    const float sc = (which == 0) ? 0.18033688f : 1.0f;
#pragma unroll
    for (int mt = 0; mt < 4; ++mt) {
      const int rl0 = wr * 64 + mt * 16 + lg * 4;
#pragma unroll
      for (int nt = 0; nt < 4; ++nt) {
        const int cl = wc * 64 + nt * 16 + lr;
        const float bv = bias[bn + cl];
#pragma unroll
        for (int r = 0; r < 4; ++r) {
          const int rl = rl0 + r;
          *(u16*)((char*)T + rl * 256 + ((cl * 2) ^ ((rl & 7) << 4))) =
              f2bf((acc[mt][nt][r] + bv) * sc);
        }
      }
    }
  }
  __syncthreads();

  const int b = bm >> 11;
  const int nbase = bm & 2047;
  if (which == 0) {
#pragma unroll
    for (int i = 0; i < 8; ++i) {
      const int c = i * 256 + tid;
      const int rl = c >> 4, dch = c & 15;
      uint4v v =
          *(const uint4v*)((const char*)T + rl * 256 + ((dch * 16) ^ ((rl & 7) << 4)));
      const int bh = b * 16 + (bn >> 6) + (dch >> 3);
      *(uint4v*)(Qb + ((size_t)bh * 2048 + nbase + rl) * 64 + (dch & 7) * 8) = v;
    }
  } else if (which == 1) {
#pragma unroll
    for (int i = 0; i < 8; ++i) {
      const int c = i * 256 + tid;
      const int lane = c & 63, s = (c >> 6) & 7, ktl = (c >> 9) & 1, hl = c >> 10;
      const int lq = lane & 31, hi2 = lane >> 5;
      const int rl = ktl * 64 + (s & 1) * 32 + lq;
      const int cc = hl * 128 + (s >> 1) * 32 + hi2 * 16;
      uint4v v = *(const uint4v*)((const char*)T + rl * 256 + (cc ^ ((rl & 7) << 4)));
      const int bh = b * 16 + ((bn & 1023) >> 6) + hl;
      const int kt2 = (nbase >> 6) + ktl;
      *(uint4v*)(Kb + ((((size_t)bh * 32 + kt2) * 8 + s) * 64 + lane) * 8) = v;
    }
  } else {
#pragma unroll
    for (int i = 0; i < 8; ++i) {
      const int c = i * 256 + tid;
      const int lane = c & 63, s = (c >> 6) & 7, ktl = (c >> 9) & 1, hl = c >> 10;
      const int lq = lane & 31, hi2 = lane >> 5;
      const int cl = hl * 64 + (s & 1) * 32 + lq;
      const int cc = ktl * 128 + (s >> 1) * 32 + hi2 * 16;
      uint4v v = *(const uint4v*)((const char*)T + cl * 256 + (cc ^ ((cl & 7) << 4)));
      const int bh = b * 16 + ((bn & 1023) >> 6) + hl;
      const int kt2 = (nbase >> 6) + ktl;
      *(uint4v*)(Vb + ((((size_t)bh * 32 + kt2) * 8 + s) * 64 + lane) * 8) = v;
    }
  }
}

// ------- flash attention v11: 4-deep counted-vmcnt pipeline (T3/T4) --------
// Same dataflow as v10 (4 waves x 32 q-rows, shared K/V LDS tiles, no-max
// softmax, native v_exp). Sync change: 4-slot tile rotation; per kt
// {vmcnt(8) -> s_barrier -> stage(kt+3) -> ds_read+compute}. Loads stay in
// flight across 3 compute phases; the queue NEVER drains to 0 in the main
// loop (T4; m201 wait-then-barrier ordering makes cross-wave LDS visibility
// sound: each wave confirms its own share, barrier publishes).
// Grid: 32 bh x 16 qt = 512 blocks (2 blocks/CU; LDS 64 KiB/block).
__global__ __launch_bounds__(256, 2) void flash_attn11(const u16* __restrict__ Qb,
                                                       const u16* __restrict__ Kp,
                                                       const u16* __restrict__ Vp,
                                                       u16* __restrict__ AO) {
  const int bh = blockIdx.x & 31;
  const int qt = blockIdx.x >> 5;   // 0..15
  const int tid = threadIdx.x;
  const int w = tid >> 6;
  const int lane = tid & 63;
  const int lq = lane & 31;
  const int hi = lane >> 5;
  const int q0 = qt * 128 + w * 32;

  __shared__ u16 Kld[4][4096];  // 4-slot rotation, 8 KiB per tile
  __shared__ u16 Vld[4][4096];

  const u16* Qg = Qb + ((size_t)bh * 2048 + q0 + lq) * 64 + 8 * hi;
  bf16x8 qf[4];
#pragma unroll
  for (int t = 0; t < 4; ++t) qf[t] = *(const bf16x8*)(Qg + 16 * t);

  const u16* Kg = Kp + (size_t)bh * (32 * 4096);
  const u16* Vg = Vp + (size_t)bh * (32 * 4096);

  f32x16 ot0 = {}, ot1 = {};
  float lacc[8] = {};

  // stage one K+V tile (4 gloads per thread = 16 KB per block-tile)
  auto stage = [&](int slot, int kt) {
    const size_t src = (size_t)kt * 4096;
    gload_lds16(Kg + src + tid * 8, &Kld[slot][tid * 8]);
    gload_lds16(Kg + src + 2048 + tid * 8, &Kld[slot][2048 + tid * 8]);
    gload_lds16(Vg + src + tid * 8, &Vld[slot][tid * 8]);
    gload_lds16(Vg + src + 2048 + tid * 8, &Vld[slot][2048 + tid * 8]);
  };

  auto compute = [&](int slot) {
    // K fragments from LDS (conflict-free lane-stride-16B)
    bf16x8 kf[8];
#pragma unroll
    for (int s = 0; s < 8; ++s)
      kf[s] = *(const bf16x8*)&Kld[slot][s * 512 + lane * 8];

    f32x16 sa = {}, sb = {};
    __builtin_amdgcn_s_setprio(1);
#pragma unroll
    for (int t = 0; t < 4; ++t) {
      sa = __builtin_amdgcn_mfma_f32_32x32x16_bf16(kf[2 * t], qf[t], sa, 0, 0, 0);
      sb = __builtin_amdgcn_mfma_f32_32x32x16_bf16(kf[2 * t + 1], qf[t], sb, 0, 0, 0);
    }
    __builtin_amdgcn_s_setprio(0);

    bf16x8 vf[8];
#pragma unroll
    for (int s = 0; s < 8; ++s)
      vf[s] = *(const bf16x8*)&Vld[slot][s * 512 + lane * 8];

    // no-max softmax: P = exp2(S'), native v_exp_f32
#pragma unroll
    for (int r = 0; r < 16; ++r) {
      sa[r] = __builtin_amdgcn_exp2f(sa[r]);
      sb[r] = __builtin_amdgcn_exp2f(sb[r]);
    }
#pragma unroll
    for (int r = 0; r < 8; ++r)
      lacc[r] += (sa[r] + sa[r + 8]) + (sb[r] + sb[r + 8]);

    unsigned Ua[8], Ub[8];
#pragma unroll
    for (int s = 0; s < 4; ++s)
#pragma unroll
      for (int m2 = 0; m2 < 2; ++m2) {
        Ua[s * 2 + m2] = cvt_pk_bf16(sa[4 * s + 2 * m2], sa[4 * s + 2 * m2 + 1]);
        Ub[s * 2 + m2] = cvt_pk_bf16(sb[4 * s + 2 * m2], sb[4 * s + 2 * m2 + 1]);
      }
    bf16x8 pfrag[4];
#pragma unroll
    for (int t = 0; t < 4; ++t) {
      const unsigned* U = (t < 2) ? Ua : Ub;
      const int tt = t & 1;
      unsigned w0 = U[(2 * tt) * 2 + 0], w2 = U[(2 * tt + 1) * 2 + 0];
      unsigned w1 = U[(2 * tt) * 2 + 1], w3 = U[(2 * tt + 1) * 2 + 1];
      perm32swap(w0, w2);
      perm32swap(w1, w3);
      uint4v uu = {w0, w1, w2, w3};
      pfrag[t] = __builtin_bit_cast(bf16x8, uu);
    }

    __builtin_amdgcn_s_setprio(1);
#pragma unroll
    for (int t = 0; t < 4; ++t) {
      ot0 = __builtin_amdgcn_mfma_f32_32x32x16_bf16(vf[2 * t], pfrag[t], ot0, 0, 0, 0);
      ot1 = __builtin_amdgcn_mfma_f32_32x32x16_bf16(vf[2 * t + 1], pfrag[t], ot1, 0, 0, 0);
    }
    __builtin_amdgcn_s_setprio(0);
  };

  // prologue: 3 tiles in flight (12 loads outstanding per thread)
  stage(0, 0);
  stage(1, 1);
  stage(2, 2);

  // main loop kt = 0..28: always stages kt+3
  for (int kt = 0; kt < 29; ++kt) {
    WAITVM("8");                      // own tile-kt loads done (kt+1..kt+3 fly)
    __builtin_amdgcn_s_barrier();     // everyone's tile-kt landed; slot kt-1 free
    stage((kt + 3) & 3, kt + 3);      // refill freed slot
    compute(kt & 3);
  }
  // kt = 29 (outstanding: 29,30,31 = 12)
  WAITVM("8");
  __builtin_amdgcn_s_barrier();
  compute(29 & 3);
  // kt = 30 (outstanding: 30,31 = 8)
  WAITVM("4");
  __builtin_amdgcn_s_barrier();
  compute(30 & 3);
  // kt = 31 (outstanding: 31 = 4)
  WAITVM("0");
  __builtin_amdgcn_s_barrier();
  compute(31 & 3);

  // ---- epilogue: exact row sum, normalize, store ----
  float lsum = ((lacc[0] + lacc[1]) + (lacc[2] + lacc[3])) +
               ((lacc[4] + lacc[5]) + (lacc[6] + lacc[7]));
  lsum += __shfl_xor(lsum, 32, 64);
  const float inv = 1.0f / lsum;

  const int b = bh >> 4, h = bh & 15;
  u16* Ao = AO + ((size_t)(b * 2048 + q0 + lq)) * 1024 + h * 64;
#pragma unroll
  for (int s = 0; s < 4; ++s) {
    {
      const int d = 8 * s + 4 * hi;
      ushort4v pk;
#pragma unroll
      for (int i = 0; i < 4; ++i) pk[i] = f2bf(ot0[4 * s + i] * inv);
      *(ushort4v*)(Ao + d) = pk;
    }
    {
      const int d = 32 + 8 * s + 4 * hi;
      ushort4v pk;
#pragma unroll
      for (int i = 0; i < 4; ++i) pk[i] = f2bf(ot1[4 * s + i] * inv);
      *(ushort4v*)(Ao + d) = pk;
    }
  }
}

// ---------------- launch ----------------
extern "C" void kernel_launch(void* const* d_in, const int* in_sizes, int n_in,
                              void* d_out, int out_size, void* d_ws, size_t ws_size,
                              hipStream_t stream) {
  const float* x = (const float*)d_in[0];
  const float* w_qkv = (const float*)d_in[1];
  const float* b_qkv = (const float*)d_in[2];
  const float* w_proj = (const float*)d_in[3];
  const float* b_proj = (const float*)d_in[4];
  float* out = (float*)d_out;

  char* ws = (char*)d_ws;
  u16* xb = (u16*)(ws);                          // 8 MiB  [4096][1024]
  u16* wqT = (u16*)(ws + (8ull << 20));          // 6 MiB  [3072][1024]
  u16* wpT = (u16*)(ws + (14ull << 20));         // 2 MiB  [1024][1024]
  u16* Qb = (u16*)(ws + (16ull << 20));          // 8 MiB  [32][2048][64]
  u16* Kp = (u16*)(ws + (24ull << 20));          // 8 MiB  packed frags
  u16* Vp = (u16*)(ws + (32ull << 20));          // 8 MiB  packed frags
  u16* AO = (u16*)(ws + (40ull << 20));          // 8 MiB  [4096][1024]

  cvt_bf16<<<dim3(2048), dim3(256), 0, stream>>>(x, xb, 4194304);
  trans_w<<<dim3(16, 48), dim3(256), 0, stream>>>(w_qkv, wqT, 1024, 3072);
  trans_w<<<dim3(16, 16), dim3(256), 0, stream>>>(w_proj, wpT, 1024, 1024);
  gemm_bt<0><<<dim3(32, 24), dim3(256), 0, stream>>>(xb, wqT, 4096, 3072, 1024,
                                                     b_qkv, nullptr, Qb, Kp, Vp);
  flash_attn11<<<dim3(512), dim3(256), 0, stream>>>(Qb, Kp, Vp, AO);
  gemm_bt<1><<<dim3(32, 8), dim3(256), 0, stream>>>(AO, wpT, 4096, 1024, 1024,
                                                    b_proj, out, nullptr, nullptr,
                                                    nullptr);
}

// Round 13
// 108.924 us; speedup vs baseline: 1.0093x; 1.0093x over previous
//
#include <hip/hip_runtime.h>

// Requires ws_size >= 48 MiB.
typedef short bf16x8 __attribute__((ext_vector_type(8)));
typedef float f32x4 __attribute__((ext_vector_type(4)));
typedef float f32x16 __attribute__((ext_vector_type(16)));
typedef unsigned short ushort8 __attribute__((ext_vector_type(8)));
typedef unsigned short ushort4v __attribute__((ext_vector_type(4)));
typedef unsigned int uint4v __attribute__((ext_vector_type(4)));
typedef unsigned short u16;

__device__ inline u16 f2bf(float f) {
  unsigned int u = __float_as_uint(f);
  u += 0x7fffu + ((u >> 16) & 1u);
  return (u16)(u >> 16);
}

__device__ inline unsigned cvt_pk_bf16(float lo, float hi2) {
  unsigned r;
  asm("v_cvt_pk_bf16_f32 %0, %1, %2" : "=v"(r) : "v"(lo), "v"(hi2));
  return r;
}

// NOTE: only safe with two DISTINCT live inputs (R5 bug: a==b coalesces).
__device__ inline void perm32swap(unsigned& a, unsigned& b) {
  asm("v_permlane32_swap_b32 %0, %1" : "+v"(a), "+v"(b));
}

__device__ inline void gload_lds16(const u16* g, u16* l) {
  __builtin_amdgcn_global_load_lds(
      (const __attribute__((address_space(1))) unsigned int*)g,
      (__attribute__((address_space(3))) unsigned int*)l, 16, 0, 0);
}

// ---------------- elementwise f32 -> bf16 ----------------
__global__ __launch_bounds__(256) void cvt_bf16(const float* __restrict__ in,
                                                u16* __restrict__ out, int n) {
  int i = (blockIdx.x * 256 + threadIdx.x) * 8;
  if (i >= n) return;
  float4 a = *(const float4*)(in + i);
  float4 b = *(const float4*)(in + i + 4);
  ushort8 o;
  o[0] = f2bf(a.x); o[1] = f2bf(a.y); o[2] = f2bf(a.z); o[3] = f2bf(a.w);
  o[4] = f2bf(b.x); o[5] = f2bf(b.y); o[6] = f2bf(b.z); o[7] = f2bf(b.w);
  *(ushort8*)(out + i) = o;
}

// ---------------- W[K][N] f32 -> Wt[N][K] bf16 ----------------
__global__ __launch_bounds__(256) void trans_w(const float* __restrict__ W,
                                               u16* __restrict__ Wt, int K, int N) {
  const int k0 = blockIdx.x * 64, n0 = blockIdx.y * 64;
  const int tx = threadIdx.x & 63, ty = threadIdx.x >> 6;
  __shared__ float t[64][65];
#pragma unroll
  for (int i = 0; i < 16; ++i) {
    int r = i * 4 + ty;
    t[r][tx] = W[(size_t)(k0 + r) * N + n0 + tx];
  }
  __syncthreads();
#pragma unroll
  for (int i = 0; i < 16; ++i) {
    int r = i * 4 + ty;
    Wt[(size_t)(n0 + r) * K + k0 + tx] = f2bf(t[tx][r]);
  }
}

// ---------------- GEMM: C[M][N] = A[M][K] * Bt[N][K]^T ----------------
// 2-phase pipelined; swizzled LDS; MODE 0: fragment-packed Q/K/V epilogue
// (Q scaled by 0.125*log2e so attention can use exp2 directly),
// MODE 1: bias + f32 out.
template <int MODE>
__global__ __launch_bounds__(256) void gemm_bt(
    const u16* __restrict__ A, const u16* __restrict__ Bt, int M, int N, int K,
    const float* __restrict__ bias, float* __restrict__ outF,
    u16* __restrict__ Qb, u16* __restrict__ Kb, u16* __restrict__ Vb) {
  const int bm = blockIdx.x * 128;
  const int bn = blockIdx.y * 128;
  const int tid = threadIdx.x;
  const int wid = tid >> 6;
  const int lr = tid & 15;
  const int lg = (tid >> 4) & 3;
  const int wr = wid >> 1, wc = wid & 1;

  __shared__ u16 smem[32768];
  u16* Ab0 = smem;
  u16* Ab1 = smem + 8192;
  u16* Bb0 = smem + 16384;
  u16* Bb1 = smem + 24576;

  f32x4 acc[4][4] = {};

  const int rowi = tid >> 3;
  const int sslot = ((tid & 7) ^ (rowi & 7)) * 8;
  const u16* Ag = A + (size_t)bm * K;
  const u16* Bg = Bt + (size_t)bn * K;
  const int nkt = K >> 6;

  auto stage = [&](u16* Ad, u16* Bd, int kt) {
    const int kof = kt << 6;
#pragma unroll
    for (int i = 0; i < 4; ++i) {
      const int row = i * 32 + rowi;
      gload_lds16(Ag + (size_t)row * K + kof + sslot, Ad + (i * 32 + wid * 8) * 64);
      gload_lds16(Bg + (size_t)row * K + kof + sslot, Bd + (i * 32 + wid * 8) * 64);
    }
  };

  stage(Ab0, Bb0, 0);
  __syncthreads();

  for (int kt = 0; kt < nkt; ++kt) {
    const int p = kt & 1;
    const char* Ard = (const char*)(p ? Ab1 : Ab0);
    const char* Brd = (const char*)(p ? Bb1 : Bb0);
    bf16x8 af[4], bfr[4];
#pragma unroll
    for (int t = 0; t < 4; ++t) {
      const int ra = wr * 64 + t * 16 + lr;
      const int rb = wc * 64 + t * 16 + lr;
      af[t] = *(const bf16x8*)(Ard + ra * 128 + ((lg * 16) ^ ((ra & 7) << 4)));
      bfr[t] = *(const bf16x8*)(Brd + rb * 128 + ((lg * 16) ^ ((rb & 7) << 4)));
    }
    if (kt + 1 < nkt) stage(p ? Ab0 : Ab1, p ? Bb0 : Bb1, kt + 1);
    __builtin_amdgcn_s_setprio(1);
#pragma unroll
    for (int mt = 0; mt < 4; ++mt)
#pragma unroll
      for (int nt = 0; nt < 4; ++nt)
        acc[mt][nt] = __builtin_amdgcn_mfma_f32_16x16x32_bf16(
            af[mt], bfr[nt], acc[mt][nt], 0, 0, 0);
    __builtin_amdgcn_s_setprio(0);
#pragma unroll
    for (int t = 0; t < 4; ++t) {
      const int ra = wr * 64 + t * 16 + lr;
      const int rb = wc * 64 + t * 16 + lr;
      af[t] = *(const bf16x8*)(Ard + ra * 128 + ((64 + lg * 16) ^ ((ra & 7) << 4)));
      bfr[t] = *(const bf16x8*)(Brd + rb * 128 + ((64 + lg * 16) ^ ((rb & 7) << 4)));
    }
    __builtin_amdgcn_s_setprio(1);
#pragma unroll
    for (int mt = 0; mt < 4; ++mt)
#pragma unroll
      for (int nt = 0; nt < 4; ++nt)
        acc[mt][nt] = __builtin_amdgcn_mfma_f32_16x16x32_bf16(
            af[mt], bfr[nt], acc[mt][nt], 0, 0, 0);
    __builtin_amdgcn_s_setprio(0);
    __syncthreads();
  }

  if (MODE == 1) {
#pragma unroll
    for (int mt = 0; mt < 4; ++mt) {
      const int row0 = bm + wr * 64 + mt * 16 + lg * 4;
#pragma unroll
      for (int nt = 0; nt < 4; ++nt) {
        const int col = bn + wc * 64 + nt * 16 + lr;
        const float bv = bias[col];
#pragma unroll
        for (int r = 0; r < 4; ++r)
          outF[(size_t)(row0 + r) * N + col] = acc[mt][nt][r] + bv;
      }
    }
    return;
  }

  u16* T = smem;
  const int which = bn >> 10;

  if (which == 2) {
#pragma unroll
    for (int nt = 0; nt < 4; ++nt) {
      const int cl = wc * 64 + nt * 16 + lr;
      const float bv = bias[bn + cl];
#pragma unroll
      for (int mt = 0; mt < 4; ++mt) {
        const int rlb = wr * 128 + mt * 32 + lg * 8;
        ushort4v pk;
#pragma unroll
        for (int r = 0; r < 4; ++r) pk[r] = f2bf(acc[mt][nt][r] + bv);
        *(ushort4v*)((char*)T + cl * 256 + (rlb ^ ((cl & 7) << 4))) = pk;
      }
    }
  } else {
    // Q gets 0.125 (1/sqrt(64)) * log2(e) so flash can use exp2 directly.
    const float sc = (which == 0) ? 0.18033688f : 1.0f;
#pragma unroll
    for (int mt = 0; mt < 4; ++mt) {
      const int rl0 = wr * 64 + mt * 16 + lg * 4;
#pragma unroll
      for (int nt = 0; nt < 4; ++nt) {
        const int cl = wc * 64 + nt * 16 + lr;
        const float bv = bias[bn + cl];
#pragma unroll
        for (int r = 0; r < 4; ++r) {
          const int rl = rl0 + r;
          *(u16*)((char*)T + rl * 256 + ((cl * 2) ^ ((rl & 7) << 4))) =
              f2bf((acc[mt][nt][r] + bv) * sc);
        }
      }
    }
  }
  __syncthreads();

  const int b = bm >> 11;
  const int nbase = bm & 2047;
  if (which == 0) {
#pragma unroll
    for (int i = 0; i < 8; ++i) {
      const int c = i * 256 + tid;
      const int rl = c >> 4, dch = c & 15;
      uint4v v =
          *(const uint4v*)((const char*)T + rl * 256 + ((dch * 16) ^ ((rl & 7) << 4)));
      const int bh = b * 16 + (bn >> 6) + (dch >> 3);
      *(uint4v*)(Qb + ((size_t)bh * 2048 + nbase + rl) * 64 + (dch & 7) * 8) = v;
    }
  } else if (which == 1) {
#pragma unroll
    for (int i = 0; i < 8; ++i) {
      const int c = i * 256 + tid;
      const int lane = c & 63, s = (c >> 6) & 7, ktl = (c >> 9) & 1, hl = c >> 10;
      const int lq = lane & 31, hi2 = lane >> 5;
      const int rl = ktl * 64 + (s & 1) * 32 + lq;
      const int cc = hl * 128 + (s >> 1) * 32 + hi2 * 16;
      uint4v v = *(const uint4v*)((const char*)T + rl * 256 + (cc ^ ((rl & 7) << 4)));
      const int bh = b * 16 + ((bn & 1023) >> 6) + hl;
      const int kt2 = (nbase >> 6) + ktl;
      *(uint4v*)(Kb + ((((size_t)bh * 32 + kt2) * 8 + s) * 64 + lane) * 8) = v;
    }
  } else {
#pragma unroll
    for (int i = 0; i < 8; ++i) {
      const int c = i * 256 + tid;
      const int lane = c & 63, s = (c >> 6) & 7, ktl = (c >> 9) & 1, hl = c >> 10;
      const int lq = lane & 31, hi2 = lane >> 5;
      const int cl = hl * 64 + (s & 1) * 32 + lq;
      const int cc = ktl * 128 + (s >> 1) * 32 + hi2 * 16;
      uint4v v = *(const uint4v*)((const char*)T + cl * 256 + (cc ^ ((cl & 7) << 4)));
      const int bh = b * 16 + ((bn & 1023) >> 6) + hl;
      const int kt2 = (nbase >> 6) + ktl;
      *(uint4v*)(Vb + ((((size_t)bh * 32 + kt2) * 8 + s) * 64 + lane) * 8) = v;
    }
  }
}

// ------- flash attention v12: KVBLK=128, two staggered chains per phase -----
// Same dataflow as v10/v11 (4 waves x 32 q-rows, shared K/V LDS, no-max
// softmax, native v_exp). ILP change: each phase covers 2 kt; the 16 QK MFMAs
// interleave over 4 independent accumulators (ILP-4), exp/cvt of tile0
// overlaps QK latency, PV0 (matrix) overlaps exp1 (VALU). Barriers halve.
// Registers stay LDS-fed -> peak ~200 VGPR, safe at (256,2).
// Grid: 32 bh x 16 qt = 512 blocks (2 blocks/CU; LDS 64 KiB/block).
__global__ __launch_bounds__(256, 2) void flash_attn12(const u16* __restrict__ Qb,
                                                       const u16* __restrict__ Kp,
                                                       const u16* __restrict__ Vp,
                                                       u16* __restrict__ AO) {
  const int bh = blockIdx.x & 31;
  const int qt = blockIdx.x >> 5;   // 0..15
  const int tid = threadIdx.x;
  const int w = tid >> 6;
  const int lane = tid & 63;
  const int lq = lane & 31;
  const int hi = lane >> 5;
  const int q0 = qt * 128 + w * 32;

  __shared__ u16 Kld[2][8192];  // dbuf slot = 2 kt tiles (16 KiB)
  __shared__ u16 Vld[2][8192];

  const u16* Qg = Qb + ((size_t)bh * 2048 + q0 + lq) * 64 + 8 * hi;
  bf16x8 qf[4];
#pragma unroll
  for (int t = 0; t < 4; ++t) qf[t] = *(const bf16x8*)(Qg + 16 * t);

  const u16* Kg = Kp + (size_t)bh * (32 * 4096);
  const u16* Vg = Vp + (size_t)bh * (32 * 4096);

  f32x16 ot0 = {}, ot1 = {};
  float lacc[8] = {};

  // stage one double-tile (2 kt): 8 gloads/thread = 32 KB per block-phase
  auto stage = [&](int p, int ph) {
    const size_t src = (size_t)ph * 8192;
#pragma unroll
    for (int j = 0; j < 4; ++j) {
      gload_lds16(Kg + src + j * 2048 + tid * 8, &Kld[p][j * 2048 + tid * 8]);
      gload_lds16(Vg + src + j * 2048 + tid * 8, &Vld[p][j * 2048 + tid * 8]);
    }
  };

  auto compute = [&](int p) {
    bf16x8 kf0[8], kf1[8];
#pragma unroll
    for (int s = 0; s < 8; ++s) {
      kf0[s] = *(const bf16x8*)&Kld[p][s * 512 + lane * 8];
      kf1[s] = *(const bf16x8*)&Kld[p][4096 + s * 512 + lane * 8];
    }

    // ---- QK for both tiles, interleaved over 4 accumulators (ILP-4) ----
    f32x16 sa0 = {}, sb0 = {}, sa1 = {}, sb1 = {};
    __builtin_amdgcn_s_setprio(1);
#pragma unroll
    for (int t = 0; t < 4; ++t) {
      sa0 = __builtin_amdgcn_mfma_f32_32x32x16_bf16(kf0[2 * t], qf[t], sa0, 0, 0, 0);
      sb0 = __builtin_amdgcn_mfma_f32_32x32x16_bf16(kf0[2 * t + 1], qf[t], sb0, 0, 0, 0);
      sa1 = __builtin_amdgcn_mfma_f32_32x32x16_bf16(kf1[2 * t], qf[t], sa1, 0, 0, 0);
      sb1 = __builtin_amdgcn_mfma_f32_32x32x16_bf16(kf1[2 * t + 1], qf[t], sb1, 0, 0, 0);
    }
    __builtin_amdgcn_s_setprio(0);

    // ---- tile 0: V frags, exp, pfrag, PV (VALU here hides QK tail) ----
    bf16x8 vf0[8];
#pragma unroll
    for (int s = 0; s < 8; ++s)
      vf0[s] = *(const bf16x8*)&Vld[p][s * 512 + lane * 8];

#pragma unroll
    for (int r = 0; r < 16; ++r) {
      sa0[r] = __builtin_amdgcn_exp2f(sa0[r]);
      sb0[r] = __builtin_amdgcn_exp2f(sb0[r]);
    }
#pragma unroll
    for (int r = 0; r < 8; ++r)
      lacc[r] += (sa0[r] + sa0[r + 8]) + (sb0[r] + sb0[r + 8]);

    unsigned Ua[8], Ub[8];
#pragma unroll
    for (int s = 0; s < 4; ++s)
#pragma unroll
      for (int m2 = 0; m2 < 2; ++m2) {
        Ua[s * 2 + m2] = cvt_pk_bf16(sa0[4 * s + 2 * m2], sa0[4 * s + 2 * m2 + 1]);
        Ub[s * 2 + m2] = cvt_pk_bf16(sb0[4 * s + 2 * m2], sb0[4 * s + 2 * m2 + 1]);
      }
    bf16x8 pfrag[4];
#pragma unroll
    for (int t = 0; t < 4; ++t) {
      const unsigned* U = (t < 2) ? Ua : Ub;
      const int tt = t & 1;
      unsigned w0 = U[(2 * tt) * 2 + 0], w2 = U[(2 * tt + 1) * 2 + 0];
      unsigned w1 = U[(2 * tt) * 2 + 1], w3 = U[(2 * tt + 1) * 2 + 1];
      perm32swap(w0, w2);
      perm32swap(w1, w3);
      uint4v uu = {w0, w1, w2, w3};
      pfrag[t] = __builtin_bit_cast(bf16x8, uu);
    }
    __builtin_amdgcn_s_setprio(1);
#pragma unroll
    for (int t = 0; t < 4; ++t) {
      ot0 = __builtin_amdgcn_mfma_f32_32x32x16_bf16(vf0[2 * t], pfrag[t], ot0, 0, 0, 0);
      ot1 = __builtin_amdgcn_mfma_f32_32x32x16_bf16(vf0[2 * t + 1], pfrag[t], ot1, 0, 0, 0);
    }
    __builtin_amdgcn_s_setprio(0);

    // ---- tile 1: V frags, exp (overlaps PV0 drain), pfrag, PV ----
    bf16x8 vf1[8];
#pragma unroll
    for (int s = 0; s < 8; ++s)
      vf1[s] = *(const bf16x8*)&Vld[p][4096 + s * 512 + lane * 8];

#pragma unroll
    for (int r = 0; r < 16; ++r) {
      sa1[r] = __builtin_amdgcn_exp2f(sa1[r]);
      sb1[r] = __builtin_amdgcn_exp2f(sb1[r]);
    }
#pragma unroll
    for (int r = 0; r < 8; ++r)
      lacc[r] += (sa1[r] + sa1[r + 8]) + (sb1[r] + sb1[r + 8]);

#pragma unroll
    for (int s = 0; s < 4; ++s)
#pragma unroll
      for (int m2 = 0; m2 < 2; ++m2) {
        Ua[s * 2 + m2] = cvt_pk_bf16(sa1[4 * s + 2 * m2], sa1[4 * s + 2 * m2 + 1]);
        Ub[s * 2 + m2] = cvt_pk_bf16(sb1[4 * s + 2 * m2], sb1[4 * s + 2 * m2 + 1]);
      }
#pragma unroll
    for (int t = 0; t < 4; ++t) {
      const unsigned* U = (t < 2) ? Ua : Ub;
      const int tt = t & 1;
      unsigned w0 = U[(2 * tt) * 2 + 0], w2 = U[(2 * tt + 1) * 2 + 0];
      unsigned w1 = U[(2 * tt) * 2 + 1], w3 = U[(2 * tt + 1) * 2 + 1];
      perm32swap(w0, w2);
      perm32swap(w1, w3);
      uint4v uu = {w0, w1, w2, w3};
      pfrag[t] = __builtin_bit_cast(bf16x8, uu);
    }
    __builtin_amdgcn_s_setprio(1);
#pragma unroll
    for (int t = 0; t < 4; ++t) {
      ot0 = __builtin_amdgcn_mfma_f32_32x32x16_bf16(vf1[2 * t], pfrag[t], ot0, 0, 0, 0);
      ot1 = __builtin_amdgcn_mfma_f32_32x32x16_bf16(vf1[2 * t + 1], pfrag[t], ot1, 0, 0, 0);
    }
    __builtin_amdgcn_s_setprio(0);
  };

  stage(0, 0);
  __syncthreads();

  for (int ph = 0; ph < 16; ++ph) {
    const int p = ph & 1;
    if (ph < 15) stage(p ^ 1, ph + 1);
    compute(p);
    __syncthreads();
  }

  // ---- epilogue: exact row sum, normalize, store ----
  float lsum = ((lacc[0] + lacc[1]) + (lacc[2] + lacc[3])) +
               ((lacc[4] + lacc[5]) + (lacc[6] + lacc[7]));
  lsum += __shfl_xor(lsum, 32, 64);
  const float inv = 1.0f / lsum;

  const int b = bh >> 4, h = bh & 15;
  u16* Ao = AO + ((size_t)(b * 2048 + q0 + lq)) * 1024 + h * 64;
#pragma unroll
  for (int s = 0; s < 4; ++s) {
    {
      const int d = 8 * s + 4 * hi;
      ushort4v pk;
#pragma unroll
      for (int i = 0; i < 4; ++i) pk[i] = f2bf(ot0[4 * s + i] * inv);
      *(ushort4v*)(Ao + d) = pk;
    }
    {
      const int d = 32 + 8 * s + 4 * hi;
      ushort4v pk;
#pragma unroll
      for (int i = 0; i < 4; ++i) pk[i] = f2bf(ot1[4 * s + i] * inv);
      *(ushort4v*)(Ao + d) = pk;
    }
  }
}

// ---------------- launch ----------------
extern "C" void kernel_launch(void* const* d_in, const int* in_sizes, int n_in,
                              void* d_out, int out_size, void* d_ws, size_t ws_size,
                              hipStream_t stream) {
  const float* x = (const float*)d_in[0];
  const float* w_qkv = (const float*)d_in[1];
  const float* b_qkv = (const float*)d_in[2];
  const float* w_proj = (const float*)d_in[3];
  const float* b_proj = (const float*)d_in[4];
  float* out = (float*)d_out;

  char* ws = (char*)d_ws;
  u16* xb = (u16*)(ws);                          // 8 MiB  [4096][1024]
  u16* wqT = (u16*)(ws + (8ull << 20));          // 6 MiB  [3072][1024]
  u16* wpT = (u16*)(ws + (14ull << 20));         // 2 MiB  [1024][1024]
  u16* Qb = (u16*)(ws + (16ull << 20));          // 8 MiB  [32][2048][64]
  u16* Kp = (u16*)(ws + (24ull << 20));          // 8 MiB  packed frags
  u16* Vp = (u16*)(ws + (32ull << 20));          // 8 MiB  packed frags
  u16* AO = (u16*)(ws + (40ull << 20));          // 8 MiB  [4096][1024]

  cvt_bf16<<<dim3(2048), dim3(256), 0, stream>>>(x, xb, 4194304);
  trans_w<<<dim3(16, 48), dim3(256), 0, stream>>>(w_qkv, wqT, 1024, 3072);
  trans_w<<<dim3(16, 16), dim3(256), 0, stream>>>(w_proj, wpT, 1024, 1024);
  gemm_bt<0><<<dim3(32, 24), dim3(256), 0, stream>>>(xb, wqT, 4096, 3072, 1024,
                                                     b_qkv, nullptr, Qb, Kp, Vp);
  flash_attn12<<<dim3(512), dim3(256), 0, stream>>>(Qb, Kp, Vp, AO);
  gemm_bt<1><<<dim3(32, 8), dim3(256), 0, stream>>>(AO, wpT, 4096, 1024, 1024,
                                                    b_proj, out, nullptr, nullptr,
                                                    nullptr);
}

// Round 14
// 107.452 us; speedup vs baseline: 1.0231x; 1.0137x over previous
//
#include <hip/hip_runtime.h>

// Requires ws_size >= 48 MiB.
typedef short bf16x8 __attribute__((ext_vector_type(8)));
typedef float f32x4 __attribute__((ext_vector_type(4)));
typedef float f32x16 __attribute__((ext_vector_type(16)));
typedef unsigned short ushort8 __attribute__((ext_vector_type(8)));
typedef unsigned short ushort4v __attribute__((ext_vector_type(4)));
typedef unsigned int uint4v __attribute__((ext_vector_type(4)));
typedef unsigned short u16;

__device__ inline u16 f2bf(float f) {
  unsigned int u = __float_as_uint(f);
  u += 0x7fffu + ((u >> 16) & 1u);
  return (u16)(u >> 16);
}

__device__ inline unsigned cvt_pk_bf16(float lo, float hi2) {
  unsigned r;
  asm("v_cvt_pk_bf16_f32 %0, %1, %2" : "=v"(r) : "v"(lo), "v"(hi2));
  return r;
}

// NOTE: only safe with two DISTINCT live inputs (R5 bug: a==b coalesces).
__device__ inline void perm32swap(unsigned& a, unsigned& b) {
  asm("v_permlane32_swap_b32 %0, %1" : "+v"(a), "+v"(b));
}

__device__ inline void gload_lds16(const u16* g, u16* l) {
  __builtin_amdgcn_global_load_lds(
      (const __attribute__((address_space(1))) unsigned int*)g,
      (__attribute__((address_space(3))) unsigned int*)l, 16, 0, 0);
}

// ---------------- elementwise f32 -> bf16 ----------------
__global__ __launch_bounds__(256) void cvt_bf16(const float* __restrict__ in,
                                                u16* __restrict__ out, int n) {
  int i = (blockIdx.x * 256 + threadIdx.x) * 8;
  if (i >= n) return;
  float4 a = *(const float4*)(in + i);
  float4 b = *(const float4*)(in + i + 4);
  ushort8 o;
  o[0] = f2bf(a.x); o[1] = f2bf(a.y); o[2] = f2bf(a.z); o[3] = f2bf(a.w);
  o[4] = f2bf(b.x); o[5] = f2bf(b.y); o[6] = f2bf(b.z); o[7] = f2bf(b.w);
  *(ushort8*)(out + i) = o;
}

// ---------------- W[K][N] f32 -> Wt[N][K] bf16 ----------------
__global__ __launch_bounds__(256) void trans_w(const float* __restrict__ W,
                                               u16* __restrict__ Wt, int K, int N) {
  const int k0 = blockIdx.x * 64, n0 = blockIdx.y * 64;
  const int tx = threadIdx.x & 63, ty = threadIdx.x >> 6;
  __shared__ float t[64][65];
#pragma unroll
  for (int i = 0; i < 16; ++i) {
    int r = i * 4 + ty;
    t[r][tx] = W[(size_t)(k0 + r) * N + n0 + tx];
  }
  __syncthreads();
#pragma unroll
  for (int i = 0; i < 16; ++i) {
    int r = i * 4 + ty;
    Wt[(size_t)(n0 + r) * K + k0 + tx] = f2bf(t[tx][r]);
  }
}

// ------------- QKV GEMM: 256x256 tile, 8 waves, BK=64, 2-phase -------------
// C[4096][3072] = xb[4096][1024] * wqT[3072][1024]^T + bias, epilogue scatters
// Q (scaled by 0.125*log2e) / fragment-packed K / fragment-packed V.
// Arithmetic intensity 2x the 128^2 tile (halves staged L2/L3 traffic);
// XCD-chunked bijective block swizzle (192 = 8 x 24) for B-panel locality.
// LDS 128 KiB (A+B dbuf), 1 block/CU, (512,1) -> VGPR cap 256 (est ~210).
__global__ __launch_bounds__(512, 1) void gemm256_qkv(
    const u16* __restrict__ A, const u16* __restrict__ Bt,
    const float* __restrict__ bias, u16* __restrict__ Qb,
    u16* __restrict__ Kb, u16* __restrict__ Vb) {
  const int K = 1024;
  // XCD-chunked swizzle: dispatch lid -> XCD lid%8; give each XCD a
  // contiguous swz range (24 blocks) => consecutive bmi share one B panel.
  const int lid = blockIdx.x;
  const int swz = (lid & 7) * 24 + (lid >> 3);
  const int bm = (swz & 15) * 256;
  const int bn = (swz >> 4) * 256;

  const int tid = threadIdx.x;
  const int wid = tid >> 6;        // 0..7
  const int lane = tid & 63;
  const int lr = lane & 15;
  const int lg = (lane >> 4) & 3;
  const int wr = wid >> 2;         // 0..1  (M)
  const int wc = wid & 3;          // 0..3  (N)

  __shared__ u16 smem[65536];      // 128 KiB
  u16* Ab0 = smem;                 // [256][64] = 16384 u16 each
  u16* Ab1 = smem + 16384;
  u16* Bb0 = smem + 32768;
  u16* Bb1 = smem + 49152;

  f32x4 acc[8][4] = {};

  const int rowi = tid >> 3;       // 0..63
  const int sslot = ((tid & 7) ^ (rowi & 7)) * 8;  // pre-swizzled source slot
  const u16* Ag = A + (size_t)bm * K;
  const u16* Bg = Bt + (size_t)bn * K;

  auto stage = [&](u16* Ad, u16* Bd, int kt) {
    const int kof = kt << 6;
#pragma unroll
    for (int i = 0; i < 4; ++i) {
      const int row = i * 64 + rowi;
      gload_lds16(Ag + (size_t)row * K + kof + sslot, Ad + (i * 64 + wid * 8) * 64);
      gload_lds16(Bg + (size_t)row * K + kof + sslot, Bd + (i * 64 + wid * 8) * 64);
    }
  };

  stage(Ab0, Bb0, 0);
  __syncthreads();

  for (int kt = 0; kt < 16; ++kt) {
    const int p = kt & 1;
    const char* Ard = (const char*)(p ? Ab1 : Ab0);
    const char* Brd = (const char*)(p ? Bb1 : Bb0);
    bf16x8 af[8], bfr[4];
    // c = 0 fragments (swizzled read)
#pragma unroll
    for (int t = 0; t < 8; ++t) {
      const int ra = wr * 128 + t * 16 + lr;
      af[t] = *(const bf16x8*)(Ard + ra * 128 + ((lg * 16) ^ ((ra & 7) << 4)));
    }
#pragma unroll
    for (int t = 0; t < 4; ++t) {
      const int rb = wc * 64 + t * 16 + lr;
      bfr[t] = *(const bf16x8*)(Brd + rb * 128 + ((lg * 16) ^ ((rb & 7) << 4)));
    }
    if (kt + 1 < 16) stage(p ? Ab0 : Ab1, p ? Bb0 : Bb1, kt + 1);
    __builtin_amdgcn_s_setprio(1);
#pragma unroll
    for (int mt = 0; mt < 8; ++mt)
#pragma unroll
      for (int nt = 0; nt < 4; ++nt)
        acc[mt][nt] = __builtin_amdgcn_mfma_f32_16x16x32_bf16(
            af[mt], bfr[nt], acc[mt][nt], 0, 0, 0);
    __builtin_amdgcn_s_setprio(0);
    // c = 1 fragments
#pragma unroll
    for (int t = 0; t < 8; ++t) {
      const int ra = wr * 128 + t * 16 + lr;
      af[t] = *(const bf16x8*)(Ard + ra * 128 + ((64 + lg * 16) ^ ((ra & 7) << 4)));
    }
#pragma unroll
    for (int t = 0; t < 4; ++t) {
      const int rb = wc * 64 + t * 16 + lr;
      bfr[t] = *(const bf16x8*)(Brd + rb * 128 + ((64 + lg * 16) ^ ((rb & 7) << 4)));
    }
    __builtin_amdgcn_s_setprio(1);
#pragma unroll
    for (int mt = 0; mt < 8; ++mt)
#pragma unroll
      for (int nt = 0; nt < 4; ++nt)
        acc[mt][nt] = __builtin_amdgcn_mfma_f32_16x16x32_bf16(
            af[mt], bfr[nt], acc[mt][nt], 0, 0, 0);
    __builtin_amdgcn_s_setprio(0);
    __syncthreads();
  }

  // ---- epilogue: acc -> swizzled LDS bounce tile T (512-B rows) -> ----
  // ---- coalesced fragment-packed global stores.                     ----
  u16* T = smem;  // 128 KiB = full 256x256 bf16 tile
  const int which = bn >> 10;  // 0=Q, 1=K, 2=V (1024 % 256 == 0)

  if (which == 2) {
    // V: store transposed T[d][token] so frag chunks are row-contiguous
#pragma unroll
    for (int nt = 0; nt < 4; ++nt) {
      const int cl = wc * 64 + nt * 16 + lr;   // d col (T row)
      const float bv = bias[bn + cl];
#pragma unroll
      for (int mt = 0; mt < 8; ++mt) {
        const int rlb = wr * 256 + mt * 32 + lg * 8;  // token byte base
        ushort4v pk;
#pragma unroll
        for (int r = 0; r < 4; ++r) pk[r] = f2bf(acc[mt][nt][r] + bv);
        *(ushort4v*)((char*)T + cl * 512 + (rlb ^ ((cl & 7) << 4))) = pk;
      }
    }
  } else {
    // Q gets 0.125 (1/sqrt(64)) * log2(e) so flash can use exp2 directly.
    const float sc = (which == 0) ? 0.18033688f : 1.0f;
#pragma unroll
    for (int mt = 0; mt < 8; ++mt) {
      const int rl0 = wr * 128 + mt * 16 + lg * 4;
#pragma unroll
      for (int nt = 0; nt < 4; ++nt) {
        const int cl = wc * 64 + nt * 16 + lr;
        const float bv = bias[bn + cl];
#pragma unroll
        for (int r = 0; r < 4; ++r) {
          const int rl = rl0 + r;
          *(u16*)((char*)T + rl * 512 + ((cl * 2) ^ ((rl & 7) << 4))) =
              f2bf((acc[mt][nt][r] + bv) * sc);
        }
      }
    }
  }
  __syncthreads();

  const int b = bm >> 11;
  const int nbase = bm & 2047;
  if (which == 0) {
#pragma unroll
    for (int i = 0; i < 16; ++i) {
      const int c = i * 512 + tid;
      const int rl = c >> 5, dch = c & 31;
      uint4v v =
          *(const uint4v*)((const char*)T + rl * 512 + ((dch * 16) ^ ((rl & 7) << 4)));
      const int bh = b * 16 + (bn >> 6) + (dch >> 3);
      *(uint4v*)(Qb + ((size_t)bh * 2048 + nbase + rl) * 64 + (dch & 7) * 8) = v;
    }
  } else if (which == 1) {
    // K frags: s=2t+rtile holds K[kt2*64+rtile*32+lq][16t+8hi+j] at lane hi*32+lq
#pragma unroll
    for (int i = 0; i < 16; ++i) {
      const int c = i * 512 + tid;
      const int ln = c & 63, s = (c >> 6) & 7, ktl = (c >> 9) & 3, hl = (c >> 11) & 3;
      const int lq = ln & 31, hi2 = ln >> 5;
      const int rl = ktl * 64 + (s & 1) * 32 + lq;
      const int cc = hl * 128 + (s >> 1) * 32 + hi2 * 16;
      uint4v v = *(const uint4v*)((const char*)T + rl * 512 + (cc ^ ((rl & 7) << 4)));
      const int bh = b * 16 + ((bn & 1023) >> 6) + hl;
      const int kt2 = (nbase >> 6) + ktl;
      *(uint4v*)(Kb + ((((size_t)bh * 32 + kt2) * 8 + s) * 64 + ln) * 8) = v;
    }
  } else {
    // V frags: s=2t+dtile holds V[kt2*64+16t+8hi+j][dtile*32+lq] at lane hi*32+lq
#pragma unroll
    for (int i = 0; i < 16; ++i) {
      const int c = i * 512 + tid;
      const int ln = c & 63, s = (c >> 6) & 7, ktl = (c >> 9) & 3, hl = (c >> 11) & 3;
      const int lq = ln & 31, hi2 = ln >> 5;
      const int cl = hl * 64 + (s & 1) * 32 + lq;
      const int cc = ktl * 128 + (s >> 1) * 32 + hi2 * 16;
      uint4v v = *(const uint4v*)((const char*)T + cl * 512 + (cc ^ ((cl & 7) << 4)));
      const int bh = b * 16 + ((bn & 1023) >> 6) + hl;
      const int kt2 = (nbase >> 6) + ktl;
      *(uint4v*)(Vb + ((((size_t)bh * 32 + kt2) * 8 + s) * 64 + ln) * 8) = v;
    }
  }
}

// ---------------- proj GEMM: 128^2 tile, 2-phase (unchanged) ----------------
__global__ __launch_bounds__(256) void gemm_proj(
    const u16* __restrict__ A, const u16* __restrict__ Bt, int M, int N, int K,
    const float* __restrict__ bias, float* __restrict__ outF) {
  const int bm = blockIdx.x * 128;
  const int bn = blockIdx.y * 128;
  const int tid = threadIdx.x;
  const int wid = tid >> 6;
  const int lr = tid & 15;
  const int lg = (tid >> 4) & 3;
  const int wr = wid >> 1, wc = wid & 1;

  __shared__ u16 smem[32768];
  u16* Ab0 = smem;
  u16* Ab1 = smem + 8192;
  u16* Bb0 = smem + 16384;
  u16* Bb1 = smem + 24576;

  f32x4 acc[4][4] = {};

  const int rowi = tid >> 3;
  const int sslot = ((tid & 7) ^ (rowi & 7)) * 8;
  const u16* Ag = A + (size_t)bm * K;
  const u16* Bg = Bt + (size_t)bn * K;
  const int nkt = K >> 6;

  auto stage = [&](u16* Ad, u16* Bd, int kt) {
    const int kof = kt << 6;
#pragma unroll
    for (int i = 0; i < 4; ++i) {
      const int row = i * 32 + rowi;
      gload_lds16(Ag + (size_t)row * K + kof + sslot, Ad + (i * 32 + wid * 8) * 64);
      gload_lds16(Bg + (size_t)row * K + kof + sslot, Bd + (i * 32 + wid * 8) * 64);
    }
  };

  stage(Ab0, Bb0, 0);
  __syncthreads();

  for (int kt = 0; kt < nkt; ++kt) {
    const int p = kt & 1;
    const char* Ard = (const char*)(p ? Ab1 : Ab0);
    const char* Brd = (const char*)(p ? Bb1 : Bb0);
    bf16x8 af[4], bfr[4];
#pragma unroll
    for (int t = 0; t < 4; ++t) {
      const int ra = wr * 64 + t * 16 + lr;
      const int rb = wc * 64 + t * 16 + lr;
      af[t] = *(const bf16x8*)(Ard + ra * 128 + ((lg * 16) ^ ((ra & 7) << 4)));
      bfr[t] = *(const bf16x8*)(Brd + rb * 128 + ((lg * 16) ^ ((rb & 7) << 4)));
    }
    if (kt + 1 < nkt) stage(p ? Ab0 : Ab1, p ? Bb0 : Bb1, kt + 1);
    __builtin_amdgcn_s_setprio(1);
#pragma unroll
    for (int mt = 0; mt < 4; ++mt)
#pragma unroll
      for (int nt = 0; nt < 4; ++nt)
        acc[mt][nt] = __builtin_amdgcn_mfma_f32_16x16x32_bf16(
            af[mt], bfr[nt], acc[mt][nt], 0, 0, 0);
    __builtin_amdgcn_s_setprio(0);
#pragma unroll
    for (int t = 0; t < 4; ++t) {
      const int ra = wr * 64 + t * 16 + lr;
      const int rb = wc * 64 + t * 16 + lr;
      af[t] = *(const bf16x8*)(Ard + ra * 128 + ((64 + lg * 16) ^ ((ra & 7) << 4)));
      bfr[t] = *(const bf16x8*)(Brd + rb * 128 + ((64 + lg * 16) ^ ((rb & 7) << 4)));
    }
    __builtin_amdgcn_s_setprio(1);
#pragma unroll
    for (int mt = 0; mt < 4; ++mt)
#pragma unroll
      for (int nt = 0; nt < 4; ++nt)
        acc[mt][nt] = __builtin_amdgcn_mfma_f32_16x16x32_bf16(
            af[mt], bfr[nt], acc[mt][nt], 0, 0, 0);
    __builtin_amdgcn_s_setprio(0);
    __syncthreads();
  }

#pragma unroll
  for (int mt = 0; mt < 4; ++mt) {
    const int row0 = bm + wr * 64 + mt * 16 + lg * 4;
#pragma unroll
    for (int nt = 0; nt < 4; ++nt) {
      const int col = bn + wc * 64 + nt * 16 + lr;
      const float bv = bias[col];
#pragma unroll
      for (int r = 0; r < 4; ++r)
        outF[(size_t)(row0 + r) * N + col] = acc[mt][nt][r] + bv;
    }
  }
}

// ------- flash attention v12: KVBLK=128, two staggered chains per phase -----
// (unchanged from R13: 51.8 us, VGPR 104, no spill)
__global__ __launch_bounds__(256, 2) void flash_attn12(const u16* __restrict__ Qb,
                                                       const u16* __restrict__ Kp,
                                                       const u16* __restrict__ Vp,
                                                       u16* __restrict__ AO) {
  const int bh = blockIdx.x & 31;
  const int qt = blockIdx.x >> 5;   // 0..15
  const int tid = threadIdx.x;
  const int w = tid >> 6;
  const int lane = tid & 63;
  const int lq = lane & 31;
  const int hi = lane >> 5;
  const int q0 = qt * 128 + w * 32;

  __shared__ u16 Kld[2][8192];  // dbuf slot = 2 kt tiles (16 KiB)
  __shared__ u16 Vld[2][8192];

  const u16* Qg = Qb + ((size_t)bh * 2048 + q0 + lq) * 64 + 8 * hi;
  bf16x8 qf[4];
#pragma unroll
  for (int t = 0; t < 4; ++t) qf[t] = *(const bf16x8*)(Qg + 16 * t);

  const u16* Kg = Kp + (size_t)bh * (32 * 4096);
  const u16* Vg = Vp + (size_t)bh * (32 * 4096);

  f32x16 ot0 = {}, ot1 = {};
  float lacc[8] = {};

  auto stage = [&](int p, int ph) {
    const size_t src = (size_t)ph * 8192;
#pragma unroll
    for (int j = 0; j < 4; ++j) {
      gload_lds16(Kg + src + j * 2048 + tid * 8, &Kld[p][j * 2048 + tid * 8]);
      gload_lds16(Vg + src + j * 2048 + tid * 8, &Vld[p][j * 2048 + tid * 8]);
    }
  };

  auto compute = [&](int p) {
    bf16x8 kf0[8], kf1[8];
#pragma unroll
    for (int s = 0; s < 8; ++s) {
      kf0[s] = *(const bf16x8*)&Kld[p][s * 512 + lane * 8];
      kf1[s] = *(const bf16x8*)&Kld[p][4096 + s * 512 + lane * 8];
    }

    f32x16 sa0 = {}, sb0 = {}, sa1 = {}, sb1 = {};
    __builtin_amdgcn_s_setprio(1);
#pragma unroll
    for (int t = 0; t < 4; ++t) {
      sa0 = __builtin_amdgcn_mfma_f32_32x32x16_bf16(kf0[2 * t], qf[t], sa0, 0, 0, 0);
      sb0 = __builtin_amdgcn_mfma_f32_32x32x16_bf16(kf0[2 * t + 1], qf[t], sb0, 0, 0, 0);
      sa1 = __builtin_amdgcn_mfma_f32_32x32x16_bf16(kf1[2 * t], qf[t], sa1, 0, 0, 0);
      sb1 = __builtin_amdgcn_mfma_f32_32x32x16_bf16(kf1[2 * t + 1], qf[t], sb1, 0, 0, 0);
    }
    __builtin_amdgcn_s_setprio(0);

    bf16x8 vf0[8];
#pragma unroll
    for (int s = 0; s < 8; ++s)
      vf0[s] = *(const bf16x8*)&Vld[p][s * 512 + lane * 8];

#pragma unroll
    for (int r = 0; r < 16; ++r) {
      sa0[r] = __builtin_amdgcn_exp2f(sa0[r]);
      sb0[r] = __builtin_amdgcn_exp2f(sb0[r]);
    }
#pragma unroll
    for (int r = 0; r < 8; ++r)
      lacc[r] += (sa0[r] + sa0[r + 8]) + (sb0[r] + sb0[r + 8]);

    unsigned Ua[8], Ub[8];
#pragma unroll
    for (int s = 0; s < 4; ++s)
#pragma unroll
      for (int m2 = 0; m2 < 2; ++m2) {
        Ua[s * 2 + m2] = cvt_pk_bf16(sa0[4 * s + 2 * m2], sa0[4 * s + 2 * m2 + 1]);
        Ub[s * 2 + m2] = cvt_pk_bf16(sb0[4 * s + 2 * m2], sb0[4 * s + 2 * m2 + 1]);
      }
    bf16x8 pfrag[4];
#pragma unroll
    for (int t = 0; t < 4; ++t) {
      const unsigned* U = (t < 2) ? Ua : Ub;
      const int tt = t & 1;
      unsigned w0 = U[(2 * tt) * 2 + 0], w2 = U[(2 * tt + 1) * 2 + 0];
      unsigned w1 = U[(2 * tt) * 2 + 1], w3 = U[(2 * tt + 1) * 2 + 1];
      perm32swap(w0, w2);
      perm32swap(w1, w3);
      uint4v uu = {w0, w1, w2, w3};
      pfrag[t] = __builtin_bit_cast(bf16x8, uu);
    }
    __builtin_amdgcn_s_setprio(1);
#pragma unroll
    for (int t = 0; t < 4; ++t) {
      ot0 = __builtin_amdgcn_mfma_f32_32x32x16_bf16(vf0[2 * t], pfrag[t], ot0, 0, 0, 0);
      ot1 = __builtin_amdgcn_mfma_f32_32x32x16_bf16(vf0[2 * t + 1], pfrag[t], ot1, 0, 0, 0);
    }
    __builtin_amdgcn_s_setprio(0);

    bf16x8 vf1[8];
#pragma unroll
    for (int s = 0; s < 8; ++s)
      vf1[s] = *(const bf16x8*)&Vld[p][4096 + s * 512 + lane * 8];

#pragma unroll
    for (int r = 0; r < 16; ++r) {
      sa1[r] = __builtin_amdgcn_exp2f(sa1[r]);
      sb1[r] = __builtin_amdgcn_exp2f(sb1[r]);
    }
#pragma unroll
    for (int r = 0; r < 8; ++r)
      lacc[r] += (sa1[r] + sa1[r + 8]) + (sb1[r] + sb1[r + 8]);

#pragma unroll
    for (int s = 0; s < 4; ++s)
#pragma unroll
      for (int m2 = 0; m2 < 2; ++m2) {
        Ua[s * 2 + m2] = cvt_pk_bf16(sa1[4 * s + 2 * m2], sa1[4 * s + 2 * m2 + 1]);
        Ub[s * 2 + m2] = cvt_pk_bf16(sb1[4 * s + 2 * m2], sb1[4 * s + 2 * m2 + 1]);
      }
#pragma unroll
    for (int t = 0; t < 4; ++t) {
      const unsigned* U = (t < 2) ? Ua : Ub;
      const int tt = t & 1;
      unsigned w0 = U[(2 * tt) * 2 + 0], w2 = U[(2 * tt + 1) * 2 + 0];
      unsigned w1 = U[(2 * tt) * 2 + 1], w3 = U[(2 * tt + 1) * 2 + 1];
      perm32swap(w0, w2);
      perm32swap(w1, w3);
      uint4v uu = {w0, w1, w2, w3};
      pfrag[t] = __builtin_bit_cast(bf16x8, uu);
    }
    __builtin_amdgcn_s_setprio(1);
#pragma unroll
    for (int t = 0; t < 4; ++t) {
      ot0 = __builtin_amdgcn_mfma_f32_32x32x16_bf16(vf1[2 * t], pfrag[t], ot0, 0, 0, 0);
      ot1 = __builtin_amdgcn_mfma_f32_32x32x16_bf16(vf1[2 * t + 1], pfrag[t], ot1, 0, 0, 0);
    }
    __builtin_amdgcn_s_setprio(0);
  };

  stage(0, 0);
  __syncthreads();

  for (int ph = 0; ph < 16; ++ph) {
    const int p = ph & 1;
    if (ph < 15) stage(p ^ 1, ph + 1);
    compute(p);
    __syncthreads();
  }

  float lsum = ((lacc[0] + lacc[1]) + (lacc[2] + lacc[3])) +
               ((lacc[4] + lacc[5]) + (lacc[6] + lacc[7]));
  lsum += __shfl_xor(lsum, 32, 64);
  const float inv = 1.0f / lsum;

  const int b = bh >> 4, h = bh & 15;
  u16* Ao = AO + ((size_t)(b * 2048 + q0 + lq)) * 1024 + h * 64;
#pragma unroll
  for (int s = 0; s < 4; ++s) {
    {
      const int d = 8 * s + 4 * hi;
      ushort4v pk;
#pragma unroll
      for (int i = 0; i < 4; ++i) pk[i] = f2bf(ot0[4 * s + i] * inv);
      *(ushort4v*)(Ao + d) = pk;
    }
    {
      const int d = 32 + 8 * s + 4 * hi;
      ushort4v pk;
#pragma unroll
      for (int i = 0; i < 4; ++i) pk[i] = f2bf(ot1[4 * s + i] * inv);
      *(ushort4v*)(Ao + d) = pk;
    }
  }
}

// ---------------- launch ----------------
extern "C" void kernel_launch(void* const* d_in, const int* in_sizes, int n_in,
                              void* d_out, int out_size, void* d_ws, size_t ws_size,
                              hipStream_t stream) {
  const float* x = (const float*)d_in[0];
  const float* w_qkv = (const float*)d_in[1];
  const float* b_qkv = (const float*)d_in[2];
  const float* w_proj = (const float*)d_in[3];
  const float* b_proj = (const float*)d_in[4];
  float* out = (float*)d_out;

  char* ws = (char*)d_ws;
  u16* xb = (u16*)(ws);                          // 8 MiB  [4096][1024]
  u16* wqT = (u16*)(ws + (8ull << 20));          // 6 MiB  [3072][1024]
  u16* wpT = (u16*)(ws + (14ull << 20));         // 2 MiB  [1024][1024]
  u16* Qb = (u16*)(ws + (16ull << 20));          // 8 MiB  [32][2048][64]
  u16* Kp = (u16*)(ws + (24ull << 20));          // 8 MiB  packed frags
  u16* Vp = (u16*)(ws + (32ull << 20));          // 8 MiB  packed frags
  u16* AO = (u16*)(ws + (40ull << 20));          // 8 MiB  [4096][1024]

  cvt_bf16<<<dim3(2048), dim3(256), 0, stream>>>(x, xb, 4194304);
  trans_w<<<dim3(16, 48), dim3(256), 0, stream>>>(w_qkv, wqT, 1024, 3072);
  trans_w<<<dim3(16, 16), dim3(256), 0, stream>>>(w_proj, wpT, 1024, 1024);
  gemm256_qkv<<<dim3(192), dim3(512), 0, stream>>>(xb, wqT, b_qkv, Qb, Kp, Vp);
  flash_attn12<<<dim3(512), dim3(256), 0, stream>>>(Qb, Kp, Vp, AO);
  gemm_proj<<<dim3(32, 8), dim3(256), 0, stream>>>(AO, wpT, 4096, 1024, 1024,
                                                   b_proj, out);
}